// Round 8
// baseline (185.972 us; speedup 1.0000x reference)
//
#include <hip/hip_runtime.h>
#include <hip/hip_bf16.h>

#define NN 128
#define CC 1001
#define RR 51
#define KK 10
#define NK (NN*KK)              // 1280
#define BT_ELEMS (NN*KK*NN*KK) // 1,638,400 = NK*NK
#define CAP 688                 // LDS row capacity (distinct classes ~723; overflow -> global path)
#define W_BIN_C 1.0f
#define MIX_C 10000.0f

typedef float f4_t __attribute__((ext_vector_type(4)));
typedef f4_t f4u __attribute__((aligned(4)));   // 4-byte-aligned float4 load

// ---------------- prep: exp(rel_scores) + top-k (labels, unary, class counts) ----------------
__global__ __launch_bounds__(256) void prep_kernel(const float* __restrict__ roi,
                                                   const float* __restrict__ rel,
                                                   float* __restrict__ exp_rel,
                                                   int* __restrict__ labels,
                                                   float* __restrict__ unary,
                                                   int* __restrict__ count) {
    int blk = blockIdx.x;
    if (blk < 104) {
        const f4_t* in4 = (const f4_t*)rel;
        f4_t* out4 = (f4_t*)exp_rel;
        for (int i = blk * 256 + threadIdx.x; i < (NN * NN * RR) / 4; i += 104 * 256) {
            f4_t v = in4[i];
            f4_t e;
            e.x = expf(v.x); e.y = expf(v.y); e.z = expf(v.z); e.w = expf(v.w);
            out4[i] = e;
        }
        return;
    }
    int a = blk - 104;
    int lane = threadIdx.x;
    if (lane >= 64) return;
    const float* rowp = roi + a * CC;
    float v[16];
    #pragma unroll
    for (int j = 0; j < 16; ++j) {
        int c = lane + 64 * j;
        v[j] = (c < CC) ? rowp[c] : -1e30f;
    }
    for (int k = 0; k < KK; ++k) {
        float bv = v[0]; int bj = 0;
        #pragma unroll
        for (int j = 1; j < 16; ++j) if (v[j] > bv) { bv = v[j]; bj = j; }  // ascending: lowest idx on tie
        int bc = lane + 64 * bj;
        #pragma unroll
        for (int m = 32; m > 0; m >>= 1) {
            float v2 = __shfl_xor(bv, m, 64);
            int   c2 = __shfl_xor(bc, m, 64);
            if (v2 > bv || (v2 == bv && c2 < bc)) { bv = v2; bc = c2; }
        }
        if (lane == (bc & 63)) {
            int j = bc >> 6;
            #pragma unroll
            for (int jj = 0; jj < 16; ++jj) if (jj == j) v[jj] = -1e30f;
        }
        if (lane == 0) {
            labels[a * KK + k] = bc;
            unary[a * KK + k]  = logf(bv);
            atomicAdd(&count[bc], 1);
        }
    }
}

// ---------------- build E (class-sorted, pre-decoded) + segment starts ----------------
// E[pos] = (cls << 21) | (b << 14) | (b*KK + l); segstart[c] = exclusive prefix.
__global__ __launch_bounds__(256) void build_kernel(const int* __restrict__ labels,
                                                    const int* __restrict__ count,
                                                    int* __restrict__ E,
                                                    int* __restrict__ segstart) {
    __shared__ int s[1024];
    __shared__ int cur[CC];
    int t = threadIdx.x;
    #pragma unroll
    for (int j = 0; j < 4; ++j) {
        int i = t + 256 * j;
        s[i] = (i < CC) ? count[i] : 0;
        if (i < CC) cur[i] = 0;
    }
    __syncthreads();
    for (int off = 1; off < 1024; off <<= 1) {
        int v[4];
        #pragma unroll
        for (int j = 0; j < 4; ++j) {
            int i = t + 256 * j;
            v[j] = s[i] + ((i >= off) ? s[i - off] : 0);
        }
        __syncthreads();
        #pragma unroll
        for (int j = 0; j < 4; ++j) s[t + 256 * j] = v[j];
        __syncthreads();
    }
    #pragma unroll
    for (int j = 0; j < 4; ++j) {
        int i = t + 256 * j;
        if (i < CC) segstart[i] = s[i] - count[i];
    }
    for (int e = t; e < NK; e += 256) {
        int cls = labels[e];
        int b = e / KK;
        int slot = atomicAdd(&cur[cls], 1);
        int pos = s[cls] - count[cls] + slot;    // exclusive prefix + rank
        E[pos] = (cls << 21) | (b << 14) | e;
    }
}

// ---------------- class_dots: block per class x; stage used relmat[x,*] rows in LDS once ----------------
// raw[p,q] = dot(relmat[x, cls_q, :], exp_rel[a_p, b_q, :]) for all p with cls_p==x, all 1280 q.
// 8-lane group per dot: lanes 0..5 two f4 (r 0..47), lane 6 one f4 (r 48..51, [51]=0 pad), lane 7 idle.
__global__ __launch_bounds__(1024) void class_dots_kernel(const float* __restrict__ relmat,
                                                          const float* __restrict__ exp_rel,
                                                          const int* __restrict__ E,
                                                          const int* __restrict__ count,
                                                          const int* __restrict__ segstart,
                                                          float* __restrict__ bt) {
    int x = blockIdx.x;
    int cnt = count[x];
    if (cnt == 0) return;
    if (cnt > 32) cnt = 32;
    int seg = segstart[x];
    int t = threadIdx.x;

    extern __shared__ char lds[];
    int*   sMeta = (int*)lds;                    // [1280]: (uidx<<21)|(b<<14)|col
    int*   sCls  = sMeta + 1280;                 // [1280]
    int*   sP    = sCls + 1280;                  // [32]
    float* rows  = (float*)(sP + 32);            // [CAP][52]
    int*   sScan = (int*)rows;                   // temp [2048] (before staging)

    for (int i = t; i < NK; i += 1024) {
        int e = E[i];
        sCls[i]  = e >> 21;
        sMeta[i] = e & 0x1FFFFF;
    }
    if (t < cnt) sP[t] = E[seg + t] & 0x1FFFFF;
    __syncthreads();

    // inclusive scan of segment-head flags -> uidx
    #pragma unroll
    for (int j = 0; j < 2; ++j) {
        int i = t + 1024 * j;
        int f = 0;
        if (i < NK) f = (i == 0) || (sCls[i] != sCls[i - 1]);
        sScan[i] = f;
    }
    __syncthreads();
    for (int off = 1; off < 2048; off <<= 1) {
        int v0 = sScan[t]        + ((t        >= off) ? sScan[t - off]        : 0);
        int v1 = sScan[t + 1024] + ((t + 1024 >= off) ? sScan[t + 1024 - off] : 0);
        __syncthreads();
        sScan[t] = v0; sScan[t + 1024] = v1;
        __syncthreads();
    }
    #pragma unroll
    for (int j = 0; j < 2; ++j) {
        int i = t + 1024 * j;
        if (i < NK) sMeta[i] |= (sScan[i] - 1) << 21;
    }
    __syncthreads();   // sScan dead; rows area reusable

    // stage unique rows into LDS: 64 groups of 16 lanes, entry i = grp + 64*round
    {
        int grp = t >> 4, ln = t & 15;
        for (int round = 0; round < 20; ++round) {
            int i = grp + 64 * round;
            bool head = (i < NK) && ((i == 0) || (sCls[i] != sCls[i - 1]));
            if (head) {
                int u = sMeta[i] >> 21;
                if (u < CAP) {
                    const float* src = relmat + ((size_t)x * CC + sCls[i]) * RR;
                    float* dst = rows + u * 52;
                    if (ln < 12) {
                        *(f4_t*)(dst + ln * 4) = *(const f4u*)(src + ln * 4);      // r 0..47
                    } else if (ln == 12) {
                        f4_t v = *(const f4u*)(src + 47);                          // r 47..50 (in-bounds)
                        dst[47] = v.x; dst[48] = v.y; dst[49] = v.z; dst[50] = v.w;
                    } else if (ln == 13) {
                        dst[51] = 0.f;                                             // pad
                    }
                }
            }
        }
    }
    __syncthreads();

    int g = t >> 3, sub = t & 7;
    bool act  = sub < 7;
    bool act1 = sub < 6;
    int r0 = (sub < 6) ? sub * 8 : 48;
    int r1 = sub * 8 + 4;
    f4_t zero; zero.x = zero.y = zero.z = zero.w = 0.f;

    for (int p = 0; p < cnt; ++p) {
        int pe = sP[p];
        int colp = pe & 16383;
        int ap   = (pe >> 14) & 127;
        const float* epb = exp_rel + ap * (NN * RR);
        float* outrow = bt + colp * NK;
        for (int qi = g; qi < NK; qi += 128) {
            int me = sMeta[qi];
            int u    = me >> 21;
            int bq   = (me >> 14) & 127;
            int colq = me & 16383;
            f4_t c0 = zero, c1 = zero, e0 = zero, e1 = zero;
            if (u < CAP) {
                const float* lr = rows + u * 52;
                if (act)  c0 = *(const f4_t*)(lr + r0);   // 16B-aligned LDS read
                if (act1) c1 = *(const f4_t*)(lr + r1);
            } else {
                const float* gr = relmat + ((size_t)x * CC + sCls[qi]) * RR;
                if (sub < 6) {
                    c0 = *(const f4u*)(gr + r0);
                    c1 = *(const f4u*)(gr + r1);
                } else if (sub == 6) {
                    f4_t v = *(const f4u*)(gr + 47);      // avoid OOB at last relmat row
                    c0.x = v.y; c0.y = v.z; c0.z = v.w; c0.w = 0.f;
                }
            }
            const float* ep = epb + bq * RR;
            if (act)  e0 = *(const f4u*)(ep + r0);        // sub6 reads ep[48..51]; [51] x 0-coeff
            if (act1) e1 = *(const f4u*)(ep + r1);
            float s = c0.x*e0.x + c0.y*e0.y + c0.z*e0.z + c0.w*e0.w
                    + c1.x*e1.x + c1.y*e1.y + c1.z*e1.z + c1.w*e1.w;
            s += __shfl_xor(s, 4, 64);
            s += __shfl_xor(s, 2, 64);
            s += __shfl_xor(s, 1, 64);
            if (sub == 0) outrow[colq] = s;
        }
    }
}

// ---------------- bt = log(0.5*(raw + raw^T)); zero when a==b (in place) ----------------
__global__ __launch_bounds__(256) void symlog_kernel(float* __restrict__ bt) {
    int i = blockIdx.x * 256 + threadIdx.x;
    int l = i % KK;
    int b = (i / KK) % NN;
    int k = (i / (KK * NN)) % KK;
    int a = i / (KK * NN * KK);
    if (a > b) return;
    if (a == b) { bt[i] = 0.0f; return; }
    int j = ((b * KK + l) * NN + a) * KK + k;
    float xx = bt[i], yy = bt[j];
    float v = logf(0.5f * (xx + yy));
    bt[i] = v;
    bt[j] = v;
}

// ---------------- mean-field round: 10 waves, wave k owns row k ----------------
__global__ __launch_bounds__(640) void round_kernel(const float* __restrict__ bt,
                                                    const float* __restrict__ unary,
                                                    const float* __restrict__ Qin,
                                                    float* __restrict__ Qout,
                                                    int uniform) {
    int a = blockIdx.x, t = threadIdx.x;
    int wave = t >> 6, lane = t & 63;
    __shared__ float sQ[NK];
    __shared__ float smsg[KK];
    if (!uniform && t < NK / 4) ((f4_t*)sQ)[t] = ((const f4_t*)Qin)[t];
    __syncthreads();
    const f4_t* row = (const f4_t*)(bt + (a * KK + wave) * NK);
    float acc = 0.f;
    if (uniform) {
        #pragma unroll
        for (int j = 0; j < 5; ++j) {
            f4_t r = row[lane + 64 * j];
            acc += r.x + r.y + r.z + r.w;
        }
        acc *= (1.0f / (float)KK);
    } else {
        const f4_t* q4 = (const f4_t*)sQ;
        #pragma unroll
        for (int j = 0; j < 5; ++j) {
            f4_t r = row[lane + 64 * j];
            f4_t q = q4[lane + 64 * j];
            acc += r.x * q.x + r.y * q.y + r.z * q.z + r.w * q.w;
        }
    }
    #pragma unroll
    for (int m = 32; m > 0; m >>= 1) acc += __shfl_xor(acc, m, 64);
    if (lane == 0) smsg[wave] = acc;
    __syncthreads();
    if (t == 0) {
        float e[KK], m = -1e30f;
        #pragma unroll
        for (int k = 0; k < KK; ++k) {
            float v = W_BIN_C * smsg[k] + unary[a * KK + k];
            e[k] = v;
            if (v > m) m = v;
        }
        float s = 0.f;
        #pragma unroll
        for (int k = 0; k < KK; ++k) { e[k] = expf(e[k] - m); s += e[k]; }
        #pragma unroll
        for (int k = 0; k < KK; ++k) Qout[a * KK + k] = e[k] / s;
    }
}

// ---------------- final round fused with output scatter/mix ----------------
__global__ __launch_bounds__(640) void round_out_kernel(const float* __restrict__ bt,
                                                        const float* __restrict__ unary,
                                                        const float* __restrict__ Qin,
                                                        const float* __restrict__ roi,
                                                        const int* __restrict__ labels,
                                                        float* __restrict__ out) {
    int a = blockIdx.x, t = threadIdx.x;
    int wave = t >> 6, lane = t & 63;
    __shared__ float sQ[NK];
    __shared__ float smsg[KK];
    __shared__ float sq[KK];
    __shared__ int   sL[KK];
    if (t < NK / 4) ((f4_t*)sQ)[t] = ((const f4_t*)Qin)[t];
    if (t >= 320 && t < 320 + KK) sL[t - 320] = labels[a * KK + (t - 320)];
    __syncthreads();
    const f4_t* row = (const f4_t*)(bt + (a * KK + wave) * NK);
    const f4_t* q4  = (const f4_t*)sQ;
    float acc = 0.f;
    #pragma unroll
    for (int j = 0; j < 5; ++j) {
        f4_t r = row[lane + 64 * j];
        f4_t q = q4[lane + 64 * j];
        acc += r.x * q.x + r.y * q.y + r.z * q.z + r.w * q.w;
    }
    #pragma unroll
    for (int m = 32; m > 0; m >>= 1) acc += __shfl_xor(acc, m, 64);
    if (lane == 0) smsg[wave] = acc;
    __syncthreads();
    if (t == 0) {
        float e[KK], m = -1e30f;
        #pragma unroll
        for (int k = 0; k < KK; ++k) {
            float v = W_BIN_C * smsg[k] + unary[a * KK + k];
            e[k] = v;
            if (v > m) m = v;
        }
        float s = 0.f;
        #pragma unroll
        for (int k = 0; k < KK; ++k) { e[k] = expf(e[k] - m); s += e[k]; }
        #pragma unroll
        for (int k = 0; k < KK; ++k) sq[k] = e[k] / s;
    }
    __syncthreads();
    for (int c = t; c < CC; c += 640) {
        float q = 0.f;
        #pragma unroll
        for (int k = 0; k < KK; ++k) if (sL[k] == c) q = sq[k];
        out[a * CC + c] = (roi[a * CC + c] + MIX_C * q) / (1.0f + MIX_C);
    }
}

extern "C" void kernel_launch(void* const* d_in, const int* in_sizes, int n_in,
                              void* d_out, int out_size, void* d_ws, size_t ws_size,
                              hipStream_t stream) {
    const float* roi    = (const float*)d_in[0];  // (128, 1001)
    const float* rel    = (const float*)d_in[1];  // (16384, 51)
    const float* relmat = (const float*)d_in[2];  // (1001, 1001, 51)
    float* out = (float*)d_out;

    // workspace layout (all 16B-aligned); total ~10 MB
    char* ws = (char*)d_ws;
    size_t off = 0;
    float* bt       = (float*)(ws + off); off += (size_t)BT_ELEMS * 4;        // 6,553,600
    float* exp_rel  = (float*)(ws + off); off += (size_t)NN * NN * RR * 4;    // 3,342,336
    int*   labels   = (int*)(ws + off);   off += NK * 4;
    float* unary    = (float*)(ws + off); off += NK * 4;
    float* QA       = (float*)(ws + off); off += NK * 4;
    float* QB       = (float*)(ws + off); off += NK * 4;
    int*   E        = (int*)(ws + off);   off += NK * 4;
    int*   count    = (int*)(ws + off);   off += ((CC * 4 + 15) / 16) * 16;
    int*   segstart = (int*)(ws + off);   off += ((CC * 4 + 15) / 16) * 16;

    size_t lds_bytes = (1280 + 1280 + 32) * 4 + (size_t)CAP * 52 * 4;  // 153,472 B

    hipMemsetAsync(count, 0, CC * sizeof(int), stream);
    prep_kernel<<<104 + NN, 256, 0, stream>>>(roi, rel, exp_rel, labels, unary, count);
    build_kernel<<<1, 256, 0, stream>>>(labels, count, E, segstart);
    class_dots_kernel<<<CC, 1024, lds_bytes, stream>>>(relmat, exp_rel, E, count, segstart, bt);
    symlog_kernel<<<BT_ELEMS / 256, 256, 0, stream>>>(bt);
    round_kernel<<<NN, 640, 0, stream>>>(bt, unary, QA, QA, 1);       // round 1: uniform Q
    round_kernel<<<NN, 640, 0, stream>>>(bt, unary, QA, QB, 0);       // round 2
    round_out_kernel<<<NN, 640, 0, stream>>>(bt, unary, QB, roi, labels, out);  // round 3 + mix
}

// Round 9
// 103.422 us; speedup vs baseline: 1.7982x; 1.7982x over previous
//
#include <hip/hip_runtime.h>
#include <hip/hip_bf16.h>

#define NN 128
#define CC 1001
#define RR 51
#define KK 10
#define NK (NN*KK)              // 1280
#define BT_ELEMS (NN*KK*NN*KK) // 1,638,400 = NK*NK
#define W_BIN_C 1.0f
#define MIX_C 10000.0f

typedef float f4_t __attribute__((ext_vector_type(4)));
typedef f4_t f4u __attribute__((aligned(4)));   // 4-byte-aligned float4 load

// ---------------- prep: exp(rel_scores) + top-k (labels, unary, class counts) ----------------
__global__ __launch_bounds__(256) void prep_kernel(const float* __restrict__ roi,
                                                   const float* __restrict__ rel,
                                                   float* __restrict__ exp_rel,
                                                   int* __restrict__ labels,
                                                   float* __restrict__ unary,
                                                   int* __restrict__ count) {
    int blk = blockIdx.x;
    if (blk < 104) {
        const f4_t* in4 = (const f4_t*)rel;
        f4_t* out4 = (f4_t*)exp_rel;
        for (int i = blk * 256 + threadIdx.x; i < (NN * NN * RR) / 4; i += 104 * 256) {
            f4_t v = in4[i];
            f4_t e;
            e.x = expf(v.x); e.y = expf(v.y); e.z = expf(v.z); e.w = expf(v.w);
            out4[i] = e;
        }
        return;
    }
    int a = blk - 104;
    int lane = threadIdx.x;
    if (lane >= 64) return;
    const float* rowp = roi + a * CC;
    float v[16];
    #pragma unroll
    for (int j = 0; j < 16; ++j) {
        int c = lane + 64 * j;
        v[j] = (c < CC) ? rowp[c] : -1e30f;
    }
    for (int k = 0; k < KK; ++k) {
        float bv = v[0]; int bj = 0;
        #pragma unroll
        for (int j = 1; j < 16; ++j) if (v[j] > bv) { bv = v[j]; bj = j; }  // ascending: lowest idx on tie
        int bc = lane + 64 * bj;
        #pragma unroll
        for (int m = 32; m > 0; m >>= 1) {
            float v2 = __shfl_xor(bv, m, 64);
            int   c2 = __shfl_xor(bc, m, 64);
            if (v2 > bv || (v2 == bv && c2 < bc)) { bv = v2; bc = c2; }
        }
        if (lane == (bc & 63)) {
            int j = bc >> 6;
            #pragma unroll
            for (int jj = 0; jj < 16; ++jj) if (jj == j) v[jj] = -1e30f;
        }
        if (lane == 0) {
            labels[a * KK + k] = bc;
            unary[a * KK + k]  = logf(bv);
            atomicAdd(&count[bc], 1);
        }
    }
}

// ---------------- build E: the 1280 (b,l) entries sorted by class, pre-decoded ----------------
// E[pos] = (cls << 21) | (b << 14) | (b*KK + l). Within-class order arbitrary
// (does not affect any output value). Single block; LDS scan + atomic cursors.
__global__ __launch_bounds__(256) void build_kernel(const int* __restrict__ labels,
                                                    const int* __restrict__ count,
                                                    int* __restrict__ E) {
    __shared__ int s[1024];
    __shared__ int cur[CC];
    int t = threadIdx.x;
    #pragma unroll
    for (int j = 0; j < 4; ++j) {
        int i = t + 256 * j;
        s[i] = (i < CC) ? count[i] : 0;
        if (i < CC) cur[i] = 0;
    }
    __syncthreads();
    for (int off = 1; off < 1024; off <<= 1) {
        int v[4];
        #pragma unroll
        for (int j = 0; j < 4; ++j) {
            int i = t + 256 * j;
            v[j] = s[i] + ((i >= off) ? s[i - off] : 0);
        }
        __syncthreads();
        #pragma unroll
        for (int j = 0; j < 4; ++j) s[t + 256 * j] = v[j];
        __syncthreads();
    }
    for (int e = t; e < NK; e += 256) {
        int cls = labels[e];
        int b = e / KK;
        int slot = atomicAdd(&cur[cls], 1);
        int pos = s[cls] - count[cls] + slot;    // exclusive prefix + rank
        E[pos] = (cls << 21) | (b << 14) | e;
    }
}

// ---------------- dots: raw[colp, colq] = dot(relmat[cls_p, cls_q, :], exp_rel[a_p, b_q, :]) ----------------
// 2D grid: blockIdx.y = p (0..1279), q = blockIdx.x*32 + group. One dot per
// 8-lane group, no divisions, no LDS, no barriers. E class-sorted => q-sweep
// walks relmat[cls_p, *] in ascending address order (same row repeats are
// L1-adjacent; same-class p rows 0.5MB apart are L2-hot). 32 loads in
// flight per wave; 51200 blocks (~200/CU) for latency hiding.
__global__ __launch_bounds__(256) void dots_kernel(const float* __restrict__ relmat,
                                                   const float* __restrict__ exp_rel,
                                                   const int* __restrict__ E,
                                                   float* __restrict__ bt) {
    int p = blockIdx.y;
    int pe = E[p];                      // wave-uniform -> scalar
    int cx   = pe >> 21;
    int ap   = (pe >> 14) & 127;
    int colp = pe & 16383;

    int t = threadIdx.x;
    int g = t >> 3, sub = t & 7;
    int q = blockIdx.x * 32 + g;
    int qe = E[q];
    int cy   = qe >> 21;
    int bq   = (qe >> 14) & 127;
    int colq = qe & 16383;

    bool act0 = sub < 7, act1 = sub < 6;
    int r0 = (sub < 6) ? sub * 8 : 47;   // lane6: r=47..50, x-coeff zeroed (47 counted by lane5)
    int r1 = sub * 8 + 4;
    f4_t zero; zero.x = zero.y = zero.z = zero.w = 0.f;

    const float* rp = relmat + ((size_t)cx * CC + cy) * RR;
    const float* xp = exp_rel + (ap * NN + bq) * RR;
    f4_t c0 = act0 ? *(const f4u*)(rp + r0) : zero;
    f4_t c1 = act1 ? *(const f4u*)(rp + r1) : zero;
    f4_t e0 = act0 ? *(const f4u*)(xp + r0) : zero;
    f4_t e1 = act1 ? *(const f4u*)(xp + r1) : zero;
    if (sub == 6) c0.x = 0.f;

    float s = c0.x*e0.x + c0.y*e0.y + c0.z*e0.z + c0.w*e0.w
            + c1.x*e1.x + c1.y*e1.y + c1.z*e1.z + c1.w*e1.w;
    s += __shfl_xor(s, 4, 64);
    s += __shfl_xor(s, 2, 64);
    s += __shfl_xor(s, 1, 64);
    if (sub == 0) bt[colp * NK + colq] = s;
}

// ---------------- bt = log(0.5*(raw + raw^T)); zero when a==b (in place) ----------------
__global__ __launch_bounds__(256) void symlog_kernel(float* __restrict__ bt) {
    int i = blockIdx.x * 256 + threadIdx.x;
    int l = i % KK;
    int b = (i / KK) % NN;
    int k = (i / (KK * NN)) % KK;
    int a = i / (KK * NN * KK);
    if (a > b) return;
    if (a == b) { bt[i] = 0.0f; return; }
    int j = ((b * KK + l) * NN + a) * KK + k;
    float xx = bt[i], yy = bt[j];
    float v = logf(0.5f * (xx + yy));
    bt[i] = v;
    bt[j] = v;
}

// ---------------- mean-field round: 10 waves, wave k owns row k ----------------
__global__ __launch_bounds__(640) void round_kernel(const float* __restrict__ bt,
                                                    const float* __restrict__ unary,
                                                    const float* __restrict__ Qin,
                                                    float* __restrict__ Qout,
                                                    int uniform) {
    int a = blockIdx.x, t = threadIdx.x;
    int wave = t >> 6, lane = t & 63;
    __shared__ float sQ[NK];
    __shared__ float smsg[KK];
    if (!uniform && t < NK / 4) ((f4_t*)sQ)[t] = ((const f4_t*)Qin)[t];
    __syncthreads();
    const f4_t* row = (const f4_t*)(bt + (a * KK + wave) * NK);
    float acc = 0.f;
    if (uniform) {
        #pragma unroll
        for (int j = 0; j < 5; ++j) {
            f4_t r = row[lane + 64 * j];
            acc += r.x + r.y + r.z + r.w;
        }
        acc *= (1.0f / (float)KK);
    } else {
        const f4_t* q4 = (const f4_t*)sQ;
        #pragma unroll
        for (int j = 0; j < 5; ++j) {
            f4_t r = row[lane + 64 * j];
            f4_t q = q4[lane + 64 * j];
            acc += r.x * q.x + r.y * q.y + r.z * q.z + r.w * q.w;
        }
    }
    #pragma unroll
    for (int m = 32; m > 0; m >>= 1) acc += __shfl_xor(acc, m, 64);
    if (lane == 0) smsg[wave] = acc;
    __syncthreads();
    if (t == 0) {
        float e[KK], m = -1e30f;
        #pragma unroll
        for (int k = 0; k < KK; ++k) {
            float v = W_BIN_C * smsg[k] + unary[a * KK + k];
            e[k] = v;
            if (v > m) m = v;
        }
        float s = 0.f;
        #pragma unroll
        for (int k = 0; k < KK; ++k) { e[k] = expf(e[k] - m); s += e[k]; }
        #pragma unroll
        for (int k = 0; k < KK; ++k) Qout[a * KK + k] = e[k] / s;
    }
}

// ---------------- final round fused with output scatter/mix ----------------
__global__ __launch_bounds__(640) void round_out_kernel(const float* __restrict__ bt,
                                                        const float* __restrict__ unary,
                                                        const float* __restrict__ Qin,
                                                        const float* __restrict__ roi,
                                                        const int* __restrict__ labels,
                                                        float* __restrict__ out) {
    int a = blockIdx.x, t = threadIdx.x;
    int wave = t >> 6, lane = t & 63;
    __shared__ float sQ[NK];
    __shared__ float smsg[KK];
    __shared__ float sq[KK];
    __shared__ int   sL[KK];
    if (t < NK / 4) ((f4_t*)sQ)[t] = ((const f4_t*)Qin)[t];
    if (t >= 320 && t < 320 + KK) sL[t - 320] = labels[a * KK + (t - 320)];
    __syncthreads();
    const f4_t* row = (const f4_t*)(bt + (a * KK + wave) * NK);
    const f4_t* q4  = (const f4_t*)sQ;
    float acc = 0.f;
    #pragma unroll
    for (int j = 0; j < 5; ++j) {
        f4_t r = row[lane + 64 * j];
        f4_t q = q4[lane + 64 * j];
        acc += r.x * q.x + r.y * q.y + r.z * q.z + r.w * q.w;
    }
    #pragma unroll
    for (int m = 32; m > 0; m >>= 1) acc += __shfl_xor(acc, m, 64);
    if (lane == 0) smsg[wave] = acc;
    __syncthreads();
    if (t == 0) {
        float e[KK], m = -1e30f;
        #pragma unroll
        for (int k = 0; k < KK; ++k) {
            float v = W_BIN_C * smsg[k] + unary[a * KK + k];
            e[k] = v;
            if (v > m) m = v;
        }
        float s = 0.f;
        #pragma unroll
        for (int k = 0; k < KK; ++k) { e[k] = expf(e[k] - m); s += e[k]; }
        #pragma unroll
        for (int k = 0; k < KK; ++k) sq[k] = e[k] / s;
    }
    __syncthreads();
    for (int c = t; c < CC; c += 640) {
        float q = 0.f;
        #pragma unroll
        for (int k = 0; k < KK; ++k) if (sL[k] == c) q = sq[k];
        out[a * CC + c] = (roi[a * CC + c] + MIX_C * q) / (1.0f + MIX_C);
    }
}

extern "C" void kernel_launch(void* const* d_in, const int* in_sizes, int n_in,
                              void* d_out, int out_size, void* d_ws, size_t ws_size,
                              hipStream_t stream) {
    const float* roi    = (const float*)d_in[0];  // (128, 1001)
    const float* rel    = (const float*)d_in[1];  // (16384, 51)
    const float* relmat = (const float*)d_in[2];  // (1001, 1001, 51)
    float* out = (float*)d_out;

    // workspace layout (all 16B-aligned); total ~10 MB
    char* ws = (char*)d_ws;
    size_t off = 0;
    float* bt      = (float*)(ws + off); off += (size_t)BT_ELEMS * 4;        // 6,553,600
    float* exp_rel = (float*)(ws + off); off += (size_t)NN * NN * RR * 4;    // 3,342,336
    int*   labels  = (int*)(ws + off);   off += NK * 4;
    float* unary   = (float*)(ws + off); off += NK * 4;
    float* QA      = (float*)(ws + off); off += NK * 4;
    float* QB      = (float*)(ws + off); off += NK * 4;
    int*   E       = (int*)(ws + off);   off += NK * 4;
    int*   count   = (int*)(ws + off);   off += ((CC * 4 + 15) / 16) * 16;

    hipMemsetAsync(count, 0, CC * sizeof(int), stream);
    prep_kernel<<<104 + NN, 256, 0, stream>>>(roi, rel, exp_rel, labels, unary, count);
    build_kernel<<<1, 256, 0, stream>>>(labels, count, E);
    dots_kernel<<<dim3(40, NK), 256, 0, stream>>>(relmat, exp_rel, E, bt);
    symlog_kernel<<<BT_ELEMS / 256, 256, 0, stream>>>(bt);
    round_kernel<<<NN, 640, 0, stream>>>(bt, unary, QA, QA, 1);       // round 1: uniform Q
    round_kernel<<<NN, 640, 0, stream>>>(bt, unary, QA, QB, 0);       // round 2
    round_out_kernel<<<NN, 640, 0, stream>>>(bt, unary, QB, roi, labels, out);  // round 3 + mix
}

// Round 10
// 79.837 us; speedup vs baseline: 2.3294x; 1.2954x over previous
//
#include <hip/hip_runtime.h>
#include <hip/hip_bf16.h>

#define NN 128
#define CC 1001
#define RR 51
#define KK 10
#define NK (NN*KK)              // 1280
#define BT_ELEMS (NN*KK*NN*KK) // 1,638,400
#define W_BIN_C 1.0f
#define MIX_C 10000.0f

typedef float f4_t __attribute__((ext_vector_type(4)));
typedef f4_t f4u __attribute__((aligned(4)));   // 4-byte-aligned float4 load

// ---------------- top-k: one wave per row, all-register ----------------
__global__ __launch_bounds__(64) void topk_kernel(const float* __restrict__ roi,
                                                  int* __restrict__ labels,
                                                  float* __restrict__ unary) {
    int a = blockIdx.x, lane = threadIdx.x;
    const float* rowp = roi + a * CC;
    float v[16];
    #pragma unroll
    for (int j = 0; j < 16; ++j) {
        int c = lane + 64 * j;
        v[j] = (c < CC) ? rowp[c] : -1e30f;
    }
    for (int k = 0; k < KK; ++k) {
        float bv = v[0]; int bj = 0;
        #pragma unroll
        for (int j = 1; j < 16; ++j) if (v[j] > bv) { bv = v[j]; bj = j; }  // ascending: lowest j on tie
        int bc = lane + 64 * bj;
        #pragma unroll
        for (int m = 32; m > 0; m >>= 1) {
            float v2 = __shfl_xor(bv, m, 64);
            int   c2 = __shfl_xor(bc, m, 64);
            if (v2 > bv || (v2 == bv && c2 < bc)) { bv = v2; bc = c2; }
        }
        if (lane == (bc & 63)) {
            int j = bc >> 6;
            #pragma unroll
            for (int jj = 0; jj < 16; ++jj) if (jj == j) v[jj] = -1e30f;  // static index clear
        }
        if (lane == 0) {
            labels[a * KK + k] = bc;
            unary[a * KK + k]  = logf(bv);
        }
    }
}

// ---------------- fused raw + symmetrize + log ----------------
// XCD-swizzled block mapping: xcd = orig&7, idx = orig>>3,
// a = (idx>>7)*8 + xcd, b = idx&127. Under round-robin block->XCD dispatch,
// XCD c processes a = c, 8+c, ... sequentially, each a's full b-sweep staying
// on that XCD -> the ~1.5MB used-row set of relmat[La_k,*] is L2-resident
// across the sweep (was L3). Active counts per XCD balanced within 8%.
// 8-lane group per (k,l): lanes 0..5 two f4 (r0..47), lane 6 f4 at r=47 with
// x-coeff zeroed; both directional dots summed before one 3-step reduce.
__global__ __launch_bounds__(256) void pair_kernel(const float* __restrict__ rel_scores,
                                                   const float* __restrict__ relmat,
                                                   const int* __restrict__ labels,
                                                   float* __restrict__ bt) {
    int orig = blockIdx.x;
    int xcd = orig & 7;
    int idx = orig >> 3;
    int a = (idx >> 7) * 8 + xcd;
    int b = idx & 127;
    if (a > b) return;
    int t = threadIdx.x;
    if (a == b) {
        if (t < 100) {
            int k = t / 10, l = t % 10;
            bt[((a * KK + k) * NN + a) * KK + l] = 0.0f;
        }
        return;
    }

    __shared__ int   La[KK], Lb[KK];
    __shared__ int   baseAB[100], baseBA[100], oAB[100], oBA[100];
    __shared__ float eAB[RR], eBA[RR];

    if (t < KK)            La[t]      = labels[a * KK + t];
    else if (t < 2 * KK)   Lb[t - KK] = labels[b * KK + (t - KK)];
    if (t >= 64  && t < 64 + RR)  eAB[t - 64]  = expf(rel_scores[(a * NN + b) * RR + (t - 64)]);
    if (t >= 128 && t < 128 + RR) eBA[t - 128] = expf(rel_scores[(b * NN + a) * RR + (t - 128)]);
    __syncthreads();
    if (t < 100) {
        int k = t / 10, l = t % 10;
        baseAB[t] = (La[k] * CC + Lb[l]) * RR;
        baseBA[t] = (Lb[l] * CC + La[k]) * RR;
        oAB[t]    = ((a * KK + k) * NN + b) * KK + l;
        oBA[t]    = ((b * KK + l) * NN + a) * KK + k;
    }
    __syncthreads();

    int gid = t >> 3;      // 0..31
    int sub = t & 7;
    bool act0 = sub < 7, act1 = sub < 6;
    int r0 = (sub < 6) ? sub * 8 : 47;   // lane 6: r=47..50, x zeroed (47 counted by lane 5)
    int r1 = sub * 8 + 4;

    f4_t zero; zero.x = zero.y = zero.z = zero.w = 0.f;
    f4_t c0A = zero, c1A = zero, c0B = zero, c1B = zero;
    if (sub < 6) {
        c0A.x = eAB[r0];   c0A.y = eAB[r0+1]; c0A.z = eAB[r0+2]; c0A.w = eAB[r0+3];
        c1A.x = eAB[r1];   c1A.y = eAB[r1+1]; c1A.z = eAB[r1+2]; c1A.w = eAB[r1+3];
        c0B.x = eBA[r0];   c0B.y = eBA[r0+1]; c0B.z = eBA[r0+2]; c0B.w = eBA[r0+3];
        c1B.x = eBA[r1];   c1B.y = eBA[r1+1]; c1B.z = eBA[r1+2]; c1B.w = eBA[r1+3];
    } else if (sub == 6) {
        c0A.x = 0.f; c0A.y = eAB[48]; c0A.z = eAB[49]; c0A.w = eAB[50];
        c0B.x = 0.f; c0B.y = eBA[48]; c0B.z = eBA[49]; c0B.w = eBA[50];
    }

    f4_t A0[4], A1[4], B0[4], B1[4];
    #pragma unroll
    for (int u = 0; u < 4; ++u) {
        int kl = gid + 32 * u;
        bool h = (kl < 100);
        int kls = h ? kl : 0;
        int bA = baseAB[kls], bB = baseBA[kls];
        A0[u] = (h && act0) ? *(const f4u*)(relmat + bA + r0) : zero;
        A1[u] = (h && act1) ? *(const f4u*)(relmat + bA + r1) : zero;
        B0[u] = (h && act0) ? *(const f4u*)(relmat + bB + r0) : zero;
        B1[u] = (h && act1) ? *(const f4u*)(relmat + bB + r1) : zero;
    }
    float s[4];
    #pragma unroll
    for (int u = 0; u < 4; ++u) {
        s[u] = A0[u].x*c0A.x + A0[u].y*c0A.y + A0[u].z*c0A.z + A0[u].w*c0A.w
             + A1[u].x*c1A.x + A1[u].y*c1A.y + A1[u].z*c1A.z + A1[u].w*c1A.w
             + B0[u].x*c0B.x + B0[u].y*c0B.y + B0[u].z*c0B.z + B0[u].w*c0B.w
             + B1[u].x*c1B.x + B1[u].y*c1B.y + B1[u].z*c1B.z + B1[u].w*c1B.w;
    }
    #pragma unroll
    for (int m = 4; m > 0; m >>= 1) {
        #pragma unroll
        for (int u = 0; u < 4; ++u) s[u] += __shfl_xor(s[u], m, 64);
    }
    if (sub == 0) {
        #pragma unroll
        for (int u = 0; u < 4; ++u) {
            int kl = gid + 32 * u;
            if (kl < 100) {
                float vv = logf(0.5f * s[u]);
                bt[oAB[kl]] = vv;
                bt[oBA[kl]] = vv;
            }
        }
    }
}

// ---------------- mean-field round: 10 waves, wave k owns row k ----------------
__global__ __launch_bounds__(640) void round_kernel(const float* __restrict__ bt,
                                                    const float* __restrict__ unary,
                                                    const float* __restrict__ Qin,
                                                    float* __restrict__ Qout,
                                                    int uniform) {
    int a = blockIdx.x, t = threadIdx.x;
    int wave = t >> 6, lane = t & 63;
    __shared__ float sQ[NK];
    __shared__ float smsg[KK];
    if (!uniform && t < NK / 4) ((f4_t*)sQ)[t] = ((const f4_t*)Qin)[t];
    __syncthreads();
    const f4_t* row = (const f4_t*)(bt + (a * KK + wave) * NK);
    float acc = 0.f;
    if (uniform) {
        #pragma unroll
        for (int j = 0; j < 5; ++j) {
            f4_t r = row[lane + 64 * j];
            acc += r.x + r.y + r.z + r.w;
        }
        acc *= (1.0f / (float)KK);
    } else {
        const f4_t* q4 = (const f4_t*)sQ;
        #pragma unroll
        for (int j = 0; j < 5; ++j) {
            f4_t r = row[lane + 64 * j];
            f4_t q = q4[lane + 64 * j];
            acc += r.x * q.x + r.y * q.y + r.z * q.z + r.w * q.w;
        }
    }
    #pragma unroll
    for (int m = 32; m > 0; m >>= 1) acc += __shfl_xor(acc, m, 64);
    if (lane == 0) smsg[wave] = acc;
    __syncthreads();
    if (t == 0) {
        float e[KK], m = -1e30f;
        #pragma unroll
        for (int k = 0; k < KK; ++k) {
            float v = W_BIN_C * smsg[k] + unary[a * KK + k];
            e[k] = v;
            if (v > m) m = v;
        }
        float s = 0.f;
        #pragma unroll
        for (int k = 0; k < KK; ++k) { e[k] = expf(e[k] - m); s += e[k]; }
        #pragma unroll
        for (int k = 0; k < KK; ++k) Qout[a * KK + k] = e[k] / s;
    }
}

// ---------------- final round fused with output scatter/mix ----------------
__global__ __launch_bounds__(640) void round_out_kernel(const float* __restrict__ bt,
                                                        const float* __restrict__ unary,
                                                        const float* __restrict__ Qin,
                                                        const float* __restrict__ roi,
                                                        const int* __restrict__ labels,
                                                        float* __restrict__ out) {
    int a = blockIdx.x, t = threadIdx.x;
    int wave = t >> 6, lane = t & 63;
    __shared__ float sQ[NK];
    __shared__ float smsg[KK];
    __shared__ float sq[KK];
    __shared__ int   sL[KK];
    if (t < NK / 4) ((f4_t*)sQ)[t] = ((const f4_t*)Qin)[t];
    if (t >= 320 && t < 320 + KK) sL[t - 320] = labels[a * KK + (t - 320)];
    __syncthreads();
    const f4_t* row = (const f4_t*)(bt + (a * KK + wave) * NK);
    const f4_t* q4  = (const f4_t*)sQ;
    float acc = 0.f;
    #pragma unroll
    for (int j = 0; j < 5; ++j) {
        f4_t r = row[lane + 64 * j];
        f4_t q = q4[lane + 64 * j];
        acc += r.x * q.x + r.y * q.y + r.z * q.z + r.w * q.w;
    }
    #pragma unroll
    for (int m = 32; m > 0; m >>= 1) acc += __shfl_xor(acc, m, 64);
    if (lane == 0) smsg[wave] = acc;
    __syncthreads();
    if (t == 0) {
        float e[KK], m = -1e30f;
        #pragma unroll
        for (int k = 0; k < KK; ++k) {
            float v = W_BIN_C * smsg[k] + unary[a * KK + k];
            e[k] = v;
            if (v > m) m = v;
        }
        float s = 0.f;
        #pragma unroll
        for (int k = 0; k < KK; ++k) { e[k] = expf(e[k] - m); s += e[k]; }
        #pragma unroll
        for (int k = 0; k < KK; ++k) sq[k] = e[k] / s;
    }
    __syncthreads();
    for (int c = t; c < CC; c += 640) {
        float q = 0.f;
        #pragma unroll
        for (int k = 0; k < KK; ++k) if (sL[k] == c) q = sq[k];
        out[a * CC + c] = (roi[a * CC + c] + MIX_C * q) / (1.0f + MIX_C);
    }
}

extern "C" void kernel_launch(void* const* d_in, const int* in_sizes, int n_in,
                              void* d_out, int out_size, void* d_ws, size_t ws_size,
                              hipStream_t stream) {
    const float* roi    = (const float*)d_in[0];  // (128, 1001)
    const float* rel    = (const float*)d_in[1];  // (16384, 51)
    const float* relmat = (const float*)d_in[2];  // (1001, 1001, 51)
    float* out = (float*)d_out;

    // workspace layout (16B-aligned)
    char* ws = (char*)d_ws;
    float* bt     = (float*)ws;                                   // 6,553,600 B
    int*   labels = (int*)(ws + (size_t)BT_ELEMS * 4);            // 5,120 B
    float* unary  = (float*)(ws + (size_t)BT_ELEMS * 4 + 5120);   // 5,120 B
    float* QA     = unary + NK;
    float* QB     = QA + NK;

    topk_kernel<<<NN, 64, 0, stream>>>(roi, labels, unary);
    pair_kernel<<<NN * NN, 256, 0, stream>>>(rel, relmat, labels, bt);
    round_kernel<<<NN, 640, 0, stream>>>(bt, unary, QA, QA, 1);       // round 1: uniform Q
    round_kernel<<<NN, 640, 0, stream>>>(bt, unary, QA, QB, 0);       // round 2
    round_out_kernel<<<NN, 640, 0, stream>>>(bt, unary, QB, roi, labels, out);  // round 3 + mix
}